// Round 5
// baseline (3924.915 us; speedup 1.0000x reference)
//
#include <hip/hip_runtime.h>
#include <math.h>

#define HW 65536
#define BB 4
#define NL 5

typedef short s8v __attribute__((ext_vector_type(8)));
typedef float f4v __attribute__((ext_vector_type(4)));
typedef unsigned short u16;

__device__ __forceinline__ float leaky_f(float x){ return x >= 0.f ? x : 0.01f * x; }

__device__ __forceinline__ u16 f2bf(float x){
    union { float f; unsigned u; } v; v.f = x;
    unsigned r = v.u + 0x7FFF + ((v.u >> 16) & 1);
    return (u16)(r >> 16);
}
__device__ __forceinline__ float bf2f(u16 h){
    union { unsigned u; float f; } v; v.u = ((unsigned)h) << 16;
    return v.f;
}

// ---------------------------------------------------------------------------
// init: also zeroes the 1KB zpad page (ws is re-poisoned before every launch)
// ---------------------------------------------------------------------------
__global__ void k_init(const float* __restrict__ src, const float* __restrict__ z0,
                       float* __restrict__ images0, float* __restrict__ resid0,
                       float* __restrict__ def, u16* __restrict__ zpad){
    int p = blockIdx.x * 256 + threadIdx.x;
    int b = p >> 16, q = p & 65535;
    images0[p] = src[p];
    resid0[p]  = z0[q];
    int x = q & 255, y = q >> 8;
    def[(size_t)(b * 2 + 0) * HW + q] = (float)x;
    def[(size_t)(b * 2 + 1) * HW + q] = (float)y;
    if (blockIdx.x == 0 && threadIdx.x < 64)
        *(int4*)(zpad + threadIdx.x * 8) = make_int4(0, 0, 0, 0);
}

__global__ void k_grad(const float* __restrict__ img, float* __restrict__ gout){
    int p = blockIdx.x * 256 + threadIdx.x;
    int b = p >> 16, q = p & 65535;
    int x = q & 255, y = q >> 8;
    const float* ib = img + (size_t)b * HW;
    int xm = max(x - 1, 0), xp = min(x + 1, 255);
    int ym = max(y - 1, 0), yp = min(y + 1, 255);
    float a00 = ib[ym * 256 + xm], a01 = ib[ym * 256 + x], a02 = ib[ym * 256 + xp];
    float a10 = ib[y  * 256 + xm],                         a12 = ib[y  * 256 + xp];
    float a20 = ib[yp * 256 + xm], a21 = ib[yp * 256 + x], a22 = ib[yp * 256 + xp];
    float gx = (a02 - a00 + 2.f * (a12 - a10) + a22 - a20) * 0.125f;
    float gy = (a20 - a00 + 2.f * (a21 - a01) + a22 - a02) * 0.125f;
    gout[(size_t)(b * 2 + 0) * HW + q] = gx;
    gout[(size_t)(b * 2 + 1) * HW + q] = gy;
}

// conv2 weights -> MFMA A-fragment order (lane&15 = oc-within-tile, quad*8+j = ic)
__global__ void k_packw(const float* __restrict__ zw2, const float* __restrict__ vw2,
                        u16* __restrict__ wp){
    int idx = blockIdx.x * 256 + threadIdx.x;     // < 1,290,240
    int lane9 = idx & 511, chunk = idx >> 9;
    int nt = chunk % 7; int t = chunk / 7;
    int ks = t % 4; t >>= 2;
    int off = t % 9; t /= 9;
    int layer = t % 5, path = t / 5;
    int lane = lane9 >> 3, j = lane9 & 7;
    int ic = ks * 32 + (lane >> 4) * 8 + j;
    int oc = nt * 16 + (lane & 15);
    const float* w = path ? vw2 : zw2;
    float v = 0.f;
    if (ic < 100 && oc < 100)
        v = w[(((size_t)layer * 100 + oc) * 100 + ic) * 9 + off];
    wp[idx] = f2bf(v);
}

// conv3 weights -> B-fragment order: slot = path*5+layer; chunk = off*4+ks
__global__ void k_packw3(const float* __restrict__ zw3, const float* __restrict__ vw3,
                         u16* __restrict__ wq){
    int idx = blockIdx.x * 256 + threadIdx.x;     // < 184,320
    if (idx >= 184320) return;
    int lane9 = idx & 511, chunk = idx >> 9;
    int ks = chunk & 3; int t = chunk >> 2;
    int off = t % 9; int slot = t / 9;
    int lane = lane9 >> 3, j = lane9 & 7;
    int ic = ks * 32 + (lane >> 4) * 8 + j;
    int oc = lane & 15;
    float v = 0.f;
    if (ic < 100){
        if (slot < 5){ if (oc == 0) v = zw3[((size_t)slot * 100 + ic) * 9 + off]; }
        else { int layer = slot - 5;
               if (oc < 2) v = vw3[(((size_t)layer * 2 + oc) * 100 + ic) * 9 + off]; }
    }
    wq[idx] = f2bf(v);
}

// ---------------------------------------------------------------------------
// conv1: 3 fp32 planes -> h1 NHWC bf16[128] (leaky; oc>=100 zero)
// ---------------------------------------------------------------------------
__global__ __launch_bounds__(256)
void k_conv1(const float* __restrict__ p0, int s0, const float* __restrict__ p1, int s1,
             const float* __restrict__ p2, int s2, const float* __restrict__ w1,
             u16* __restrict__ h1, int b0){
    __shared__ float t3[300];
    __shared__ float wl[2700];
    const int tid = threadIdx.x;
    const int tX = blockIdx.x, tY = blockIdx.y, bz = blockIdx.z;
    const int b = b0 + bz;
    const int y0 = tY * 8 - 1, x0 = tX * 8 - 1;
    for (int idx = tid; idx < 300; idx += 256){
        int ch = idx / 100, p = idx - ch * 100;
        int r = p / 10, c = p - r * 10;
        int gy = y0 + r, gx = x0 + c;
        const float* pp = (ch == 0) ? p0 + (size_t)b * s0
                        : (ch == 1) ? p1 + (size_t)b * s1 : p2 + (size_t)b * s2;
        t3[idx] = ((unsigned)gy < 256u && (unsigned)gx < 256u) ? pp[gy * 256 + gx] : 0.f;
    }
    for (int idx = tid; idx < 2700; idx += 256) wl[idx] = w1[idx];
    __syncthreads();

    const int px = tid & 63, g = tid >> 6;
    const int row = px >> 3, colx = px & 7;
    float iv[27];
    #pragma unroll
    for (int c3 = 0; c3 < 3; c3++)
        #pragma unroll
        for (int dr = 0; dr < 3; dr++)
            #pragma unroll
            for (int dc = 0; dc < 3; dc++)
                iv[c3 * 9 + dr * 3 + dc] = t3[c3 * 100 + (row + dr) * 10 + colx + dc];

    const int gy = tY * 8 + row, gx = tX * 8 + colx;
    u16* dst = h1 + (((size_t)bz * HW + (size_t)(gy * 256 + gx)) << 7) + g * 32;
    #pragma unroll
    for (int s = 0; s < 4; s++){
        int ov[4];
        #pragma unroll
        for (int hp = 0; hp < 4; hp++){
            u16 lo = 0, hi = 0;
            #pragma unroll
            for (int e = 0; e < 2; e++){
                int oc = g * 32 + s * 8 + hp * 2 + e;
                u16 hv = 0;
                if (oc < 100){
                    const float* wk = &wl[oc * 27];
                    float a = 0.f;
                    #pragma unroll
                    for (int q = 0; q < 27; q++) a = fmaf(wk[q], iv[q], a);
                    hv = f2bf(leaky_f(a));
                }
                if (e) hi = hv; else lo = hv;
            }
            ov[hp] = (int)lo | ((int)hi << 16);
        }
        *(int4*)(dst + s * 8) = make_int4(ov[0], ov[1], ov[2], ov[3]);
    }
}

// ---------------------------------------------------------------------------
// conv2: 100->100 3x3 implicit GEMM, LDS-free & barrier-free.
// A=weights (M=oc, direct L2), B=acts (N=px, direct NHWC global: lane's
// 16B fragment IS contiguous memory). OOB halo lanes -> zeroed scratch page.
// block 256 = 4 waves, out tile 32x8 px; per wave 4 px-tiles x 7 oc-tiles.
// ---------------------------------------------------------------------------
__global__ __launch_bounds__(256, 3)
void k_conv2(const u16* __restrict__ h1, const u16* __restrict__ wp,
             u16* __restrict__ h2, const u16* __restrict__ zpad){
    const int tid = threadIdx.x;
    const int lane = tid & 63, wv = tid >> 6;
    const int quad = lane >> 4, m = lane & 15;
    const int tX = blockIdx.x, tY = blockIdx.y, bz = blockIdx.z;
    const size_t hbase = (size_t)bz << 16;

    f4v acc[4][7];
    #pragma unroll
    for (int t = 0; t < 4; t++)
        #pragma unroll
        for (int n = 0; n < 7; n++){
            acc[t][n][0] = 0.f; acc[t][n][1] = 0.f; acc[t][n][2] = 0.f; acc[t][n][3] = 0.f;
        }

    const u16* zp = zpad + quad * 8;
    const u16* wlane = wp + lane * 8;

    for (int off = 0; off < 9; off++){
        const int dr = off / 3, dc = off - dr * 3;
        const u16* ab[4];
        #pragma unroll
        for (int t = 0; t < 4; t++){
            int gy = tY * 8 + 2 * wv + (t >> 1) + dr - 1;
            int gx = tX * 32 + (t & 1) * 16 + m + dc - 1;
            bool ok = ((unsigned)gy < 256u) & ((unsigned)gx < 256u);
            ab[t] = ok ? h1 + ((hbase + (size_t)(gy * 256 + gx)) << 7) + quad * 8 : zp;
        }
        #pragma unroll
        for (int ks = 0; ks < 4; ks++){
            s8v bf[4];
            #pragma unroll
            for (int t = 0; t < 4; t++)
                bf[t] = *(const s8v*)(ab[t] + ks * 32);
            const u16* wk = wlane + (size_t)((off * 4 + ks) * 7) * 512;
            #pragma unroll
            for (int nt = 0; nt < 7; nt++){
                s8v af = *(const s8v*)(wk + nt * 512);
                #pragma unroll
                for (int t = 0; t < 4; t++)
                    acc[t][nt] = __builtin_amdgcn_mfma_f32_16x16x32_bf16(af, bf[t], acc[t][nt], 0, 0, 0);
            }
        }
    }

    // epilogue (verified R3/R4): oc = nt*16 + quad*4 + reg at px col m
    #pragma unroll
    for (int t = 0; t < 4; t++){
        int gy = tY * 8 + 2 * wv + (t >> 1);
        int gx = tX * 32 + (t & 1) * 16 + m;
        u16* base = h2 + ((hbase + (size_t)(gy * 256 + gx)) << 7);
        #pragma unroll
        for (int nt = 0; nt < 7; nt++){
            unsigned lo = (unsigned)f2bf(leaky_f(acc[t][nt][0])) |
                          ((unsigned)f2bf(leaky_f(acc[t][nt][1])) << 16);
            unsigned hi = (unsigned)f2bf(leaky_f(acc[t][nt][2])) |
                          ((unsigned)f2bf(leaky_f(acc[t][nt][3])) << 16);
            *(int2*)(base + nt * 16 + quad * 4) = make_int2((int)lo, (int)hi);
        }
    }
    // h2 ch 112..127 left unwritten: conv3 weights are zero for ic>=100 and
    // 0xAAAA bf16 poison is finite, so garbage*0 == 0.
}

// ---------------------------------------------------------------------------
// conv3: 100->N implicit GEMM, LDS-free. A=acts (M=px), B=weights (N=oc).
// D: row=quad*4+reg=px, col=lane&15=oc (verified R4).
// ---------------------------------------------------------------------------
template<int N>
__global__ __launch_bounds__(256, 4)
void k_conv3(const u16* __restrict__ h2, const u16* __restrict__ wq,
             const float* __restrict__ rprev, float* __restrict__ out0,
             float* __restrict__ out1, int b0, const u16* __restrict__ zpad){
    const int tid = threadIdx.x;
    const int lane = tid & 63, wv = tid >> 6;
    const int quad = lane >> 4, m = lane & 15;
    const int tX = blockIdx.x, tY = blockIdx.y, bz = blockIdx.z;
    const size_t hbase = (size_t)bz << 16;

    f4v acc[4];
    #pragma unroll
    for (int t = 0; t < 4; t++){ acc[t][0]=0.f; acc[t][1]=0.f; acc[t][2]=0.f; acc[t][3]=0.f; }

    const u16* zp = zpad + quad * 8;
    const u16* wlane = wq + lane * 8;

    for (int off = 0; off < 9; off++){
        const int dr = off / 3, dc = off - dr * 3;
        const u16* ab[4];
        #pragma unroll
        for (int t = 0; t < 4; t++){
            int gy = tY * 8 + 2 * wv + (t >> 1) + dr - 1;
            int gx = tX * 32 + (t & 1) * 16 + m + dc - 1;
            bool ok = ((unsigned)gy < 256u) & ((unsigned)gx < 256u);
            ab[t] = ok ? h2 + ((hbase + (size_t)(gy * 256 + gx)) << 7) + quad * 8 : zp;
        }
        #pragma unroll
        for (int ks = 0; ks < 4; ks++){
            s8v wf = *(const s8v*)(wlane + (size_t)(off * 4 + ks) * 512);
            #pragma unroll
            for (int t = 0; t < 4; t++){
                s8v af = *(const s8v*)(ab[t] + ks * 32);
                acc[t] = __builtin_amdgcn_mfma_f32_16x16x32_bf16(af, wf, acc[t], 0, 0, 0);
            }
        }
    }

    const int b = b0 + bz;
    #pragma unroll
    for (int t = 0; t < 4; t++){
        int gy = tY * 8 + 2 * wv + (t >> 1);
        int gx = tX * 32 + (t & 1) * 16 + quad * 4;
        size_t p = (size_t)gy * 256 + gx;
        if (N == 1){
            if (m == 0){
                float4 rp = *(const float4*)&rprev[(size_t)b * HW + p];
                float4 v = make_float4(rp.x + acc[t][0] * 0.2f, rp.y + acc[t][1] * 0.2f,
                                       rp.z + acc[t][2] * 0.2f, rp.w + acc[t][3] * 0.2f);
                *(float4*)&out0[(size_t)b * HW + p] = v;
                *(float4*)&out1[(size_t)b * HW + p] = v;
            }
        } else {
            if (m < 2){
                float4 v = make_float4(acc[t][0], acc[t][1], acc[t][2], acc[t][3]);
                *(float4*)&out0[((size_t)(b * 2) + m) * HW + p] = v;
            }
        }
    }
}

// ---------------------------------------------------------------------------
// bilinear warp + blurs + final (unchanged)
// ---------------------------------------------------------------------------
__device__ __forceinline__ float bilin(const float* __restrict__ img, float x, float y){
    float x0 = floorf(x), y0 = floorf(y);
    float wx = x - x0, wy = y - y0;
    float r = 0.f;
    #pragma unroll
    for (int dy = 0; dy < 2; dy++){
        float yi = y0 + (float)dy;
        if (yi < 0.f || yi > 255.f) continue;
        int iy = (int)yi;
        float wyv = dy ? wy : 1.f - wy;
        #pragma unroll
        for (int dx = 0; dx < 2; dx++){
            float xi = x0 + (float)dx;
            if (xi < 0.f || xi > 255.f) continue;
            int ix = (int)xi;
            float wxv = dx ? wx : 1.f - wx;
            r += wyv * wxv * img[iy * 256 + ix];
        }
    }
    return r;
}

__global__ void k_deform(const float* __restrict__ rdin, const float* __restrict__ def,
                         float* __restrict__ rdout){
    int p = blockIdx.x * 256 + threadIdx.x;
    int j = blockIdx.y;
    int b = p >> 16, q = p & 65535;
    float x = def[(size_t)(b * 2 + 0) * HW + q];
    float y = def[(size_t)(b * 2 + 1) * HW + q];
    rdout[(size_t)j * BB * HW + p] = bilin(rdin + (size_t)j * BB * HW + (size_t)b * HW, x, y);
}

__global__ void k_blur_h(const float* __restrict__ in, float* __restrict__ outb){
    __shared__ float g[51];
    __shared__ float row[306];
    __shared__ float ginv;
    int tid = threadIdx.x;
    int rid = blockIdx.x;
    int ch = rid >> 8, y = rid & 255;
    if (tid < 51){ float d = (float)tid - 25.f; g[tid] = expf(-0.005f * d * d); }
    row[tid + 25] = in[(size_t)ch * HW + y * 256 + tid];
    if (tid < 25) row[tid] = 0.f;
    if (tid >= 231) row[tid + 50] = 0.f;
    __syncthreads();
    if (tid == 0){ float s = 0.f; for (int k = 0; k < 51; k++) s += g[k]; ginv = 1.f / s; }
    __syncthreads();
    float acc = 0.f;
    for (int k = 0; k < 51; k++) acc = fmaf(g[k], row[tid + k], acc);
    outb[(size_t)ch * HW + y * 256 + tid] = acc * ginv;
}

__global__ void k_blur_v(const float* __restrict__ in, float* __restrict__ fout,
                         float* __restrict__ def){
    __shared__ float g[51];
    __shared__ float ginv;
    __shared__ float tb[82 * 64];
    int tid = threadIdx.x;
    int tX = blockIdx.x, tY = blockIdx.y, ch = blockIdx.z;
    if (tid < 51){ float d = (float)tid - 25.f; g[tid] = expf(-0.005f * d * d); }
    for (int idx = tid; idx < 82 * 64; idx += 256){
        int r = idx >> 6, c = idx & 63;
        int gy = tY * 32 + r - 25, gx = tX * 64 + c;
        tb[idx] = (gy >= 0 && gy < 256) ? in[(size_t)ch * HW + gy * 256 + gx] : 0.f;
    }
    __syncthreads();
    if (tid == 0){ float s = 0.f; for (int k = 0; k < 51; k++) s += g[k]; ginv = 1.f / s; }
    __syncthreads();
    int c = tid & 63, r0 = (tid >> 6) * 8;
    for (int k = 0; k < 8; k++){
        int r = r0 + k;
        float acc = 0.f;
        for (int t = 0; t < 51; t++) acc = fmaf(g[t], tb[(r + t) * 64 + c], acc);
        acc *= ginv;
        int y = tY * 32 + r, x = tX * 64 + c;
        fout[(size_t)ch * HW + y * 256 + x] = acc;
        def [(size_t)ch * HW + y * 256 + x] -= acc * 0.2f;
    }
}

__global__ void k_final(const float* __restrict__ def, const float* __restrict__ src,
                        const float* __restrict__ seg, const float* __restrict__ rdbase,
                        int nrd, float* __restrict__ imgout){
    int p = blockIdx.x * 256 + threadIdx.x;
    int b = p >> 16, q = p & 65535;
    float x = def[(size_t)(b * 2 + 0) * HW + q];
    float y = def[(size_t)(b * 2 + 1) * HW + q];
    float mk = bilin(seg + (size_t)b * HW, x, y);
    float s = bilin(src + (size_t)b * HW, x, y);
    float acc = 0.f;
    for (int j = 0; j < nrd; j++) acc += rdbase[(size_t)j * BB * HW + p];
    imgout[p] = s + acc * 8e-5f * mk;
}

// ---------------------------------------------------------------------------
extern "C" void kernel_launch(void* const* d_in, const int* in_sizes, int n_in,
                              void* d_out, int out_size, void* d_ws, size_t ws_size,
                              hipStream_t stream){
    const float* source = (const float*)d_in[0];
    const float* seg    = (const float*)d_in[1];
    const float* z0     = (const float*)d_in[2];
    const float* zw1    = (const float*)d_in[3];
    const float* zw2    = (const float*)d_in[4];
    const float* zw3    = (const float*)d_in[5];
    const float* vw1    = (const float*)d_in[6];
    const float* vw2    = (const float*)d_in[7];
    const float* vw3    = (const float*)d_in[8];

    float* out = (float*)d_out;
    float* images = out;                       // (6,B,1,HW)
    float* fields = out + 1572864;             // (5,B,2,HW)
    float* resid  = out + 4194304;             // (6,B,1,HW)
    float* grads  = out + 5767168;             // (6,B,2,HW)

    float* ws = (float*)d_ws;
    float* def  = ws;                          // 524288
    float* RDa  = def  + 524288;               // 1310720
    float* RDb  = RDa  + 1310720;              // 1310720
    float* vtmp = RDb  + 1310720;              // 524288
    float* btmp = vtmp + 524288;               // 524288
    u16*   zpad = (u16*)(btmp + 524288);       // 512 u16 (zeroed by k_init)
    u16*   wp   = zpad + 512;                  // 1,290,240 u16
    u16*   wq3  = wp + 1290240;                // 184,320 u16
    u16*   h1   = wq3 + 184320;

    size_t need4 = 4194304ull * 4 + 512ull * 2 + 1290240ull * 2 + 184320ull * 2
                 + 2ull * 4 * 16777216ull;
    const int HB = (ws_size >= need4) ? 4 : 1;
    u16* h2 = h1 + (size_t)HB * 8388608;       // HB*HW*128

    k_packw <<<5040, 256, 0, stream>>>(zw2, vw2, wp);
    k_packw3<<<720, 256, 0, stream>>>(zw3, vw3, wq3);
    k_init  <<<1024, 256, 0, stream>>>(source, z0, images, resid, def, zpad);
    k_grad  <<<1024, 256, 0, stream>>>(source, grads);

    float* RDcur = RDa;
    float* RDnxt = RDb;

    for (int i = 0; i < NL; i++){
        float* res_i  = resid  + (size_t)i * BB * HW;
        float* res_ip = resid  + (size_t)(i + 1) * BB * HW;
        float* img_i  = images + (size_t)i * BB * HW;
        float* img_ip = images + (size_t)(i + 1) * BB * HW;

        // ---- z path ----
        for (int b0 = 0; b0 < BB; b0 += HB){
            k_conv1<<<dim3(32, 32, HB), 256, 0, stream>>>(
                res_i, HW, img_i, HW, images, HW, zw1 + (size_t)i * 2700, h1, b0);
            k_conv2<<<dim3(8, 32, HB), 256, 0, stream>>>(
                h1, wp + (size_t)i * 129024, h2, zpad);
            k_conv3<1><<<dim3(8, 32, HB), 256, 0, stream>>>(
                h2, wq3 + (size_t)i * 18432, res_i, res_ip,
                RDnxt + (size_t)i * BB * HW, b0, zpad);
        }

        // ---- deform previously-deformed residuals (pre-update def) ----
        if (i > 0)
            k_deform<<<dim3(1024, i), 256, 0, stream>>>(RDcur, def, RDnxt);

        // ---- v path ----
        for (int b0 = 0; b0 < BB; b0 += HB){
            k_conv1<<<dim3(32, 32, HB), 256, 0, stream>>>(
                def, 2 * HW, def + HW, 2 * HW, img_i, HW, vw1 + (size_t)i * 2700, h1, b0);
            k_conv2<<<dim3(8, 32, HB), 256, 0, stream>>>(
                h1, wp + (size_t)(NL + i) * 129024, h2, zpad);
            k_conv3<2><<<dim3(8, 32, HB), 256, 0, stream>>>(
                h2, wq3 + (size_t)(NL + i) * 18432, nullptr, vtmp, nullptr, b0, zpad);
        }
        k_blur_h<<<2048, 256, 0, stream>>>(vtmp, btmp);
        k_blur_v<<<dim3(4, 8, 8), 256, 0, stream>>>(
            btmp, fields + (size_t)i * BB * 2 * HW, def);

        // ---- finalize ----
        k_final<<<1024, 256, 0, stream>>>(def, source, seg, RDnxt, i + 1, img_ip);
        k_grad<<<1024, 256, 0, stream>>>(img_ip, grads + (size_t)(i + 1) * BB * 2 * HW);

        float* t = RDcur; RDcur = RDnxt; RDnxt = t;
    }
}

// Round 6
// 2456.010 us; speedup vs baseline: 1.5981x; 1.5981x over previous
//
#include <hip/hip_runtime.h>
#include <math.h>

#define HW 65536
#define BB 4
#define NL 5

typedef short s8v __attribute__((ext_vector_type(8)));
typedef float f4v __attribute__((ext_vector_type(4)));
typedef unsigned short u16;

#define AS1 __attribute__((address_space(1)))
#define AS3 __attribute__((address_space(3)))

__device__ __forceinline__ float leaky_f(float x){ return x >= 0.f ? x : 0.01f * x; }

__device__ __forceinline__ u16 f2bf(float x){
    union { float f; unsigned u; } v; v.f = x;
    unsigned r = v.u + 0x7FFF + ((v.u >> 16) & 1);
    return (u16)(r >> 16);
}
__device__ __forceinline__ float bf2f(u16 h){
    union { unsigned u; float f; } v; v.u = ((unsigned)h) << 16;
    return v.f;
}

// ---------------------------------------------------------------------------
// init / gradient
// ---------------------------------------------------------------------------
__global__ void k_init(const float* __restrict__ src, const float* __restrict__ z0,
                       float* __restrict__ images0, float* __restrict__ resid0,
                       float* __restrict__ def){
    int p = blockIdx.x * 256 + threadIdx.x;
    int b = p >> 16, q = p & 65535;
    images0[p] = src[p];
    resid0[p]  = z0[q];
    int x = q & 255, y = q >> 8;
    def[(size_t)(b * 2 + 0) * HW + q] = (float)x;
    def[(size_t)(b * 2 + 1) * HW + q] = (float)y;
}

__global__ void k_grad(const float* __restrict__ img, float* __restrict__ gout){
    int p = blockIdx.x * 256 + threadIdx.x;
    int b = p >> 16, q = p & 65535;
    int x = q & 255, y = q >> 8;
    const float* ib = img + (size_t)b * HW;
    int xm = max(x - 1, 0), xp = min(x + 1, 255);
    int ym = max(y - 1, 0), yp = min(y + 1, 255);
    float a00 = ib[ym * 256 + xm], a01 = ib[ym * 256 + x], a02 = ib[ym * 256 + xp];
    float a10 = ib[y  * 256 + xm],                         a12 = ib[y  * 256 + xp];
    float a20 = ib[yp * 256 + xm], a21 = ib[yp * 256 + x], a22 = ib[yp * 256 + xp];
    float gx = (a02 - a00 + 2.f * (a12 - a10) + a22 - a20) * 0.125f;
    float gy = (a20 - a00 + 2.f * (a21 - a01) + a22 - a02) * 0.125f;
    gout[(size_t)(b * 2 + 0) * HW + q] = gx;
    gout[(size_t)(b * 2 + 1) * HW + q] = gy;
}

// conv2 weights -> MFMA A-fragment order, oc padded to 128 (8 nt-tiles).
// chunk = ((path*5+layer)*9*4 + off*4 + ks)*8 + nt ; within: lane*8+j
// lane&15 = oc-in-tile, (lane>>4)*8+j = ic-in-slab
__global__ void k_packw(const float* __restrict__ zw2, const float* __restrict__ vw2,
                        u16* __restrict__ wp){
    int idx = blockIdx.x * 256 + threadIdx.x;     // < 1,474,560
    int lane9 = idx & 511, chunk = idx >> 9;
    int nt = chunk & 7; int t = chunk >> 3;
    int ks = t % 4; t >>= 2;
    int off = t % 9; t /= 9;
    int layer = t % 5, path = t / 5;
    int lane = lane9 >> 3, j = lane9 & 7;
    int ic = ks * 32 + (lane >> 4) * 8 + j;
    int oc = nt * 16 + (lane & 15);
    const float* w = path ? vw2 : zw2;
    float v = 0.f;
    if (ic < 100 && oc < 100)
        v = w[(((size_t)layer * 100 + oc) * 100 + ic) * 9 + off];
    wp[idx] = f2bf(v);
}

// conv3 weights -> B-fragment order: slot = path*5+layer; chunk = off*4+ks
__global__ void k_packw3(const float* __restrict__ zw3, const float* __restrict__ vw3,
                         u16* __restrict__ wq){
    int idx = blockIdx.x * 256 + threadIdx.x;     // < 184,320
    if (idx >= 184320) return;
    int lane9 = idx & 511, chunk = idx >> 9;
    int ks = chunk & 3; int t = chunk >> 2;
    int off = t % 9; int slot = t / 9;
    int lane = lane9 >> 3, j = lane9 & 7;
    int ic = ks * 32 + (lane >> 4) * 8 + j;
    int oc = lane & 15;
    float v = 0.f;
    if (ic < 100){
        if (slot < 5){ if (oc == 0) v = zw3[((size_t)slot * 100 + ic) * 9 + off]; }
        else { int layer = slot - 5;
               if (oc < 2) v = vw3[(((size_t)layer * 2 + oc) * 100 + ic) * 9 + off]; }
    }
    wq[idx] = f2bf(v);
}

// ---------------------------------------------------------------------------
// conv1: 3 fp32 planes -> h1 NHWC bf16[128] (leaky; oc>=100 zero)
// ---------------------------------------------------------------------------
__global__ __launch_bounds__(256)
void k_conv1(const float* __restrict__ p0, int s0, const float* __restrict__ p1, int s1,
             const float* __restrict__ p2, int s2, const float* __restrict__ w1,
             u16* __restrict__ h1, int b0){
    __shared__ float t3[300];
    __shared__ float wl[2700];
    const int tid = threadIdx.x;
    const int tX = blockIdx.x, tY = blockIdx.y, bz = blockIdx.z;
    const int b = b0 + bz;
    const int y0 = tY * 8 - 1, x0 = tX * 8 - 1;
    for (int idx = tid; idx < 300; idx += 256){
        int ch = idx / 100, p = idx - ch * 100;
        int r = p / 10, c = p - r * 10;
        int gy = y0 + r, gx = x0 + c;
        const float* pp = (ch == 0) ? p0 + (size_t)b * s0
                        : (ch == 1) ? p1 + (size_t)b * s1 : p2 + (size_t)b * s2;
        t3[idx] = ((unsigned)gy < 256u && (unsigned)gx < 256u) ? pp[gy * 256 + gx] : 0.f;
    }
    for (int idx = tid; idx < 2700; idx += 256) wl[idx] = w1[idx];
    __syncthreads();

    const int px = tid & 63, g = tid >> 6;
    const int row = px >> 3, colx = px & 7;
    float iv[27];
    #pragma unroll
    for (int c3 = 0; c3 < 3; c3++)
        #pragma unroll
        for (int dr = 0; dr < 3; dr++)
            #pragma unroll
            for (int dc = 0; dc < 3; dc++)
                iv[c3 * 9 + dr * 3 + dc] = t3[c3 * 100 + (row + dr) * 10 + colx + dc];

    const int gy = tY * 8 + row, gx = tX * 8 + colx;
    u16* dst = h1 + (((size_t)bz * HW + (size_t)(gy * 256 + gx)) << 7) + g * 32;
    #pragma unroll
    for (int s = 0; s < 4; s++){
        int ov[4];
        #pragma unroll
        for (int hp = 0; hp < 4; hp++){
            u16 lo = 0, hi = 0;
            #pragma unroll
            for (int e = 0; e < 2; e++){
                int oc = g * 32 + s * 8 + hp * 2 + e;
                u16 hv = 0;
                if (oc < 100){
                    const float* wk = &wl[oc * 27];
                    float a = 0.f;
                    #pragma unroll
                    for (int q = 0; q < 27; q++) a = fmaf(wk[q], iv[q], a);
                    hv = f2bf(leaky_f(a));
                }
                if (e) hi = hv; else lo = hv;
            }
            ov[hp] = (int)lo | ((int)hi << 16);
        }
        *(int4*)(dst + s * 8) = make_int4(ov[0], ov[1], ov[2], ov[3]);
    }
}

// ---------------------------------------------------------------------------
// async DMA staging of a 34x10 halo tile, one 32-ic slab per ks (R4-proven).
// OOB lanes read ch 112..119 of px0 (guaranteed zero) with step 0.
// ---------------------------------------------------------------------------
__device__ __forceinline__ void dma_setup(const u16* __restrict__ h, size_t hbase,
                                          int y0, int x0, int tid,
                                          const u16** gp, int* gstep){
    const u16* zpad = h + (hbase << 7) + 112;
    #pragma unroll
    for (int s = 0; s < 6; s++){
        int idx = tid + s * 256;
        const u16* g = zpad; int st = 0;
        if (idx < 1360){
            int px = idx >> 2, part = idx & 3;
            int hr = px / 34, hc = px - hr * 34;
            int gy = y0 + hr, gx = x0 + hc;
            if ((unsigned)gy < 256u && (unsigned)gx < 256u){
                g = h + ((hbase + (size_t)(gy * 256 + gx)) << 7) + (part ^ ((px >> 1) & 3)) * 8;
                st = 32;
            }
        }
        gp[s] = g; gstep[s] = st;
    }
}

__device__ __forceinline__ void dma_slab(const u16** gp, const int* gstep,
                                         short* Lnxt, int wv){
    #pragma unroll
    for (int s = 0; s < 6; s++){
        __builtin_amdgcn_global_load_lds(
            (const AS1 unsigned int*)(unsigned long long)(const void*)gp[s],
            (AS3 unsigned int*)(unsigned long long)(void*)(&Lnxt[(s * 256 + wv * 64) * 8]),
            16, 0, 0);
        gp[s] += gstep[s];
    }
}

// ---------------------------------------------------------------------------
// conv2: 100->100 3x3 implicit GEMM. Wave = 4 oc-tiles (64 oc) x 8 px-tiles
// (128 px); block = 2x2 waves = 128 oc x 256 px. A=weights direct L2 with
// explicit next-window double-buffer; B=acts from DMA-staged LDS slab.
// D: row=quad*4+reg=oc, col=lane&15=px. Writes zeros to ch 100..127.
// ---------------------------------------------------------------------------
__global__ __launch_bounds__(256, 2)
void k_conv2(const u16* __restrict__ h1, const u16* __restrict__ wp, u16* __restrict__ h2){
    __shared__ __align__(16) short lds[2][12288];
    const int tid = threadIdx.x;
    const int lane = tid & 63, wv = tid >> 6;
    const int quad = lane >> 4, m = lane & 15;
    const int hhalf = wv & 1, vhalf = wv >> 1;
    const int tX = blockIdx.x, tY = blockIdx.y, bz = blockIdx.z;
    const int y0 = tY * 8 - 1, x0 = tX * 32 - 1;
    const size_t hbase = (size_t)bz << 16;

    f4v acc[4][8];
    #pragma unroll
    for (int t = 0; t < 4; t++)
        #pragma unroll
        for (int n = 0; n < 8; n++){
            acc[t][n][0] = 0.f; acc[t][n][1] = 0.f; acc[t][n][2] = 0.f; acc[t][n][3] = 0.f;
        }

    const u16* gp[6]; int gstep[6];
    dma_setup(h1, hbase, y0, x0, tid, gp, gstep);
    dma_slab(gp, gstep, lds[0], wv);

    const u16* wl = wp + lane * 8;
    s8v af[2][4];
    #pragma unroll
    for (int t = 0; t < 4; t++)                       // window (ks=0,off=0)
        af[0][t] = *(const s8v*)(wl + (size_t)(4 * hhalf + t) * 512);

    for (int ks = 0; ks < 4; ks++){
        __syncthreads();
        const short* L = lds[ks & 1];
        short* Lnxt = lds[(ks + 1) & 1];
        #pragma unroll
        for (int off = 0; off < 9; off++){
            const int kk = ks * 9 + off;
            if (off == 4 && ks < 3) dma_slab(gp, gstep, Lnxt, wv);
            if (kk < 35){                             // prefetch next window's A
                int nks = (off == 8) ? ks + 1 : ks;
                int noff = (off == 8) ? 0 : off + 1;
                #pragma unroll
                for (int t = 0; t < 4; t++)
                    af[(kk + 1) & 1][t] =
                        *(const s8v*)(wl + (size_t)((noff * 4 + nks) * 8 + 4 * hhalf + t) * 512);
            }
            const int dr = off / 3, dc = off - dr * 3;
            s8v bf[8];
            #pragma unroll
            for (int n = 0; n < 8; n++){
                int hpx = (4 * vhalf + (n >> 1) + dr) * 34 + (n & 1) * 16 + m + dc;
                bf[n] = *(const s8v*)&L[hpx * 32 + ((quad ^ ((hpx >> 1) & 3)) << 3)];
            }
            #pragma unroll
            for (int t = 0; t < 4; t++)
                #pragma unroll
                for (int n = 0; n < 8; n++)
                    acc[t][n] = __builtin_amdgcn_mfma_f32_16x16x32_bf16(
                        af[kk & 1][t], bf[n], acc[t][n], 0, 0, 0);
        }
    }

    // epilogue: oc = 64*hhalf + 16t + quad*4 + reg at px col m
    #pragma unroll
    for (int n = 0; n < 8; n++){
        int gy = tY * 8 + 4 * vhalf + (n >> 1);
        int gx = tX * 32 + (n & 1) * 16 + m;
        u16* base = h2 + ((hbase + (size_t)(gy * 256 + gx)) << 7) + 64 * hhalf;
        #pragma unroll
        for (int t = 0; t < 4; t++){
            unsigned lo = (unsigned)f2bf(leaky_f(acc[t][n][0])) |
                          ((unsigned)f2bf(leaky_f(acc[t][n][1])) << 16);
            unsigned hi = (unsigned)f2bf(leaky_f(acc[t][n][2])) |
                          ((unsigned)f2bf(leaky_f(acc[t][n][3])) << 16);
            *(int2*)(base + t * 16 + quad * 4) = make_int2((int)lo, (int)hi);
        }
    }
}

// ---------------------------------------------------------------------------
// conv3: 100->N implicit GEMM via MFMA (R4-proven). A=acts (M=px), B=weights.
// D: row=quad*4+reg=px, col=lane&15=oc.
// ---------------------------------------------------------------------------
template<int N>
__global__ __launch_bounds__(256, 2)
void k_conv3(const u16* __restrict__ h2, const u16* __restrict__ wq,
             const float* __restrict__ rprev, float* __restrict__ out0,
             float* __restrict__ out1, int b0){
    __shared__ __align__(16) short lds[2][12288];
    const int tid = threadIdx.x;
    const int lane = tid & 63, wv = tid >> 6;
    const int quad = lane >> 4, m = lane & 15;
    const int tX = blockIdx.x, tY = blockIdx.y, bz = blockIdx.z;
    const int y0 = tY * 8 - 1, x0 = tX * 32 - 1;
    const size_t hbase = (size_t)bz << 16;

    f4v acc[4];
    #pragma unroll
    for (int t = 0; t < 4; t++){ acc[t][0]=0.f; acc[t][1]=0.f; acc[t][2]=0.f; acc[t][3]=0.f; }

    const u16* gp[6]; int gstep[6];
    dma_setup(h2, hbase, y0, x0, tid, gp, gstep);
    dma_slab(gp, gstep, lds[0], wv);

    for (int ks = 0; ks < 4; ks++){
        __syncthreads();
        const short* L = lds[ks & 1];
        short* Lnxt = lds[(ks + 1) & 1];
        const bool pre = (ks < 3);
        #pragma unroll
        for (int off = 0; off < 9; off++){
            if (off == 4 && pre) dma_slab(gp, gstep, Lnxt, wv);
            const int dr = off / 3, dc = off - dr * 3;
            s8v wf = *(const s8v*)(wq + (size_t)(off * 4 + ks) * 512 + lane * 8);
            #pragma unroll
            for (int t = 0; t < 4; t++){
                int hpx = (2 * wv + (t >> 1) + dr) * 34 + (t & 1) * 16 + dc + m;
                s8v af = *(const s8v*)&L[hpx * 32 + ((quad ^ ((hpx >> 1) & 3)) << 3)];
                acc[t] = __builtin_amdgcn_mfma_f32_16x16x32_bf16(af, wf, acc[t], 0, 0, 0);
            }
        }
    }

    const int b = b0 + bz;
    #pragma unroll
    for (int t = 0; t < 4; t++){
        int gy = tY * 8 + 2 * wv + (t >> 1);
        int gx = tX * 32 + (t & 1) * 16 + quad * 4;
        size_t p = (size_t)gy * 256 + gx;
        if (N == 1){
            if (m == 0){
                float4 rp = *(const float4*)&rprev[(size_t)b * HW + p];
                float4 v = make_float4(rp.x + acc[t][0] * 0.2f, rp.y + acc[t][1] * 0.2f,
                                       rp.z + acc[t][2] * 0.2f, rp.w + acc[t][3] * 0.2f);
                *(float4*)&out0[(size_t)b * HW + p] = v;
                *(float4*)&out1[(size_t)b * HW + p] = v;
            }
        } else {
            if (m < 2){
                float4 v = make_float4(acc[t][0], acc[t][1], acc[t][2], acc[t][3]);
                *(float4*)&out0[((size_t)(b * 2) + m) * HW + p] = v;
            }
        }
    }
}

// ---------------------------------------------------------------------------
// bilinear warp + blurs + final (unchanged)
// ---------------------------------------------------------------------------
__device__ __forceinline__ float bilin(const float* __restrict__ img, float x, float y){
    float x0 = floorf(x), y0 = floorf(y);
    float wx = x - x0, wy = y - y0;
    float r = 0.f;
    #pragma unroll
    for (int dy = 0; dy < 2; dy++){
        float yi = y0 + (float)dy;
        if (yi < 0.f || yi > 255.f) continue;
        int iy = (int)yi;
        float wyv = dy ? wy : 1.f - wy;
        #pragma unroll
        for (int dx = 0; dx < 2; dx++){
            float xi = x0 + (float)dx;
            if (xi < 0.f || xi > 255.f) continue;
            int ix = (int)xi;
            float wxv = dx ? wx : 1.f - wx;
            r += wyv * wxv * img[iy * 256 + ix];
        }
    }
    return r;
}

__global__ void k_deform(const float* __restrict__ rdin, const float* __restrict__ def,
                         float* __restrict__ rdout){
    int p = blockIdx.x * 256 + threadIdx.x;
    int j = blockIdx.y;
    int b = p >> 16, q = p & 65535;
    float x = def[(size_t)(b * 2 + 0) * HW + q];
    float y = def[(size_t)(b * 2 + 1) * HW + q];
    rdout[(size_t)j * BB * HW + p] = bilin(rdin + (size_t)j * BB * HW + (size_t)b * HW, x, y);
}

__global__ void k_blur_h(const float* __restrict__ in, float* __restrict__ outb){
    __shared__ float g[51];
    __shared__ float row[306];
    __shared__ float ginv;
    int tid = threadIdx.x;
    int rid = blockIdx.x;
    int ch = rid >> 8, y = rid & 255;
    if (tid < 51){ float d = (float)tid - 25.f; g[tid] = expf(-0.005f * d * d); }
    row[tid + 25] = in[(size_t)ch * HW + y * 256 + tid];
    if (tid < 25) row[tid] = 0.f;
    if (tid >= 231) row[tid + 50] = 0.f;
    __syncthreads();
    if (tid == 0){ float s = 0.f; for (int k = 0; k < 51; k++) s += g[k]; ginv = 1.f / s; }
    __syncthreads();
    float acc = 0.f;
    for (int k = 0; k < 51; k++) acc = fmaf(g[k], row[tid + k], acc);
    outb[(size_t)ch * HW + y * 256 + tid] = acc * ginv;
}

__global__ void k_blur_v(const float* __restrict__ in, float* __restrict__ fout,
                         float* __restrict__ def){
    __shared__ float g[51];
    __shared__ float ginv;
    __shared__ float tb[82 * 64];
    int tid = threadIdx.x;
    int tX = blockIdx.x, tY = blockIdx.y, ch = blockIdx.z;
    if (tid < 51){ float d = (float)tid - 25.f; g[tid] = expf(-0.005f * d * d); }
    for (int idx = tid; idx < 82 * 64; idx += 256){
        int r = idx >> 6, c = idx & 63;
        int gy = tY * 32 + r - 25, gx = tX * 64 + c;
        tb[idx] = (gy >= 0 && gy < 256) ? in[(size_t)ch * HW + gy * 256 + gx] : 0.f;
    }
    __syncthreads();
    if (tid == 0){ float s = 0.f; for (int k = 0; k < 51; k++) s += g[k]; ginv = 1.f / s; }
    __syncthreads();
    int c = tid & 63, r0 = (tid >> 6) * 8;
    for (int k = 0; k < 8; k++){
        int r = r0 + k;
        float acc = 0.f;
        for (int t = 0; t < 51; t++) acc = fmaf(g[t], tb[(r + t) * 64 + c], acc);
        acc *= ginv;
        int y = tY * 32 + r, x = tX * 64 + c;
        fout[(size_t)ch * HW + y * 256 + x] = acc;
        def [(size_t)ch * HW + y * 256 + x] -= acc * 0.2f;
    }
}

__global__ void k_final(const float* __restrict__ def, const float* __restrict__ src,
                        const float* __restrict__ seg, const float* __restrict__ rdbase,
                        int nrd, float* __restrict__ imgout){
    int p = blockIdx.x * 256 + threadIdx.x;
    int b = p >> 16, q = p & 65535;
    float x = def[(size_t)(b * 2 + 0) * HW + q];
    float y = def[(size_t)(b * 2 + 1) * HW + q];
    float mk = bilin(seg + (size_t)b * HW, x, y);
    float s = bilin(src + (size_t)b * HW, x, y);
    float acc = 0.f;
    for (int j = 0; j < nrd; j++) acc += rdbase[(size_t)j * BB * HW + p];
    imgout[p] = s + acc * 8e-5f * mk;
}

// ---------------------------------------------------------------------------
extern "C" void kernel_launch(void* const* d_in, const int* in_sizes, int n_in,
                              void* d_out, int out_size, void* d_ws, size_t ws_size,
                              hipStream_t stream){
    const float* source = (const float*)d_in[0];
    const float* seg    = (const float*)d_in[1];
    const float* z0     = (const float*)d_in[2];
    const float* zw1    = (const float*)d_in[3];
    const float* zw2    = (const float*)d_in[4];
    const float* zw3    = (const float*)d_in[5];
    const float* vw1    = (const float*)d_in[6];
    const float* vw2    = (const float*)d_in[7];
    const float* vw3    = (const float*)d_in[8];

    float* out = (float*)d_out;
    float* images = out;                       // (6,B,1,HW)
    float* fields = out + 1572864;             // (5,B,2,HW)
    float* resid  = out + 4194304;             // (6,B,1,HW)
    float* grads  = out + 5767168;             // (6,B,2,HW)

    float* ws = (float*)d_ws;
    float* def  = ws;                          // 524288
    float* RDa  = def  + 524288;               // 1310720
    float* RDb  = RDa  + 1310720;              // 1310720
    float* vtmp = RDb  + 1310720;              // 524288
    float* btmp = vtmp + 524288;               // 524288
    u16*   wp   = (u16*)(btmp + 524288);       // 1,474,560 u16
    u16*   wq3  = wp + 1474560;                // 184,320 u16
    u16*   h1   = wq3 + 184320;

    size_t need4 = 4194304ull * 4 + 1474560ull * 2 + 184320ull * 2 + 2ull * 4 * 16777216ull;
    const int HB = (ws_size >= need4) ? 4 : 1;
    u16* h2 = h1 + (size_t)HB * 8388608;       // HB*HW*128

    k_packw <<<5760, 256, 0, stream>>>(zw2, vw2, wp);
    k_packw3<<<720, 256, 0, stream>>>(zw3, vw3, wq3);
    k_init  <<<1024, 256, 0, stream>>>(source, z0, images, resid, def);
    k_grad  <<<1024, 256, 0, stream>>>(source, grads);

    float* RDcur = RDa;
    float* RDnxt = RDb;

    for (int i = 0; i < NL; i++){
        float* res_i  = resid  + (size_t)i * BB * HW;
        float* res_ip = resid  + (size_t)(i + 1) * BB * HW;
        float* img_i  = images + (size_t)i * BB * HW;
        float* img_ip = images + (size_t)(i + 1) * BB * HW;

        // ---- z path ----
        for (int b0 = 0; b0 < BB; b0 += HB){
            k_conv1<<<dim3(32, 32, HB), 256, 0, stream>>>(
                res_i, HW, img_i, HW, images, HW, zw1 + (size_t)i * 2700, h1, b0);
            k_conv2<<<dim3(8, 32, HB), 256, 0, stream>>>(
                h1, wp + (size_t)i * 147456, h2);
            k_conv3<1><<<dim3(8, 32, HB), 256, 0, stream>>>(
                h2, wq3 + (size_t)i * 18432, res_i, res_ip,
                RDnxt + (size_t)i * BB * HW, b0);
        }

        // ---- deform previously-deformed residuals (pre-update def) ----
        if (i > 0)
            k_deform<<<dim3(1024, i), 256, 0, stream>>>(RDcur, def, RDnxt);

        // ---- v path ----
        for (int b0 = 0; b0 < BB; b0 += HB){
            k_conv1<<<dim3(32, 32, HB), 256, 0, stream>>>(
                def, 2 * HW, def + HW, 2 * HW, img_i, HW, vw1 + (size_t)i * 2700, h1, b0);
            k_conv2<<<dim3(8, 32, HB), 256, 0, stream>>>(
                h1, wp + (size_t)(NL + i) * 147456, h2);
            k_conv3<2><<<dim3(8, 32, HB), 256, 0, stream>>>(
                h2, wq3 + (size_t)(NL + i) * 18432, nullptr, vtmp, nullptr, b0);
        }
        k_blur_h<<<2048, 256, 0, stream>>>(vtmp, btmp);
        k_blur_v<<<dim3(4, 8, 8), 256, 0, stream>>>(
            btmp, fields + (size_t)i * BB * 2 * HW, def);

        // ---- finalize ----
        k_final<<<1024, 256, 0, stream>>>(def, source, seg, RDnxt, i + 1, img_ip);
        k_grad<<<1024, 256, 0, stream>>>(img_ip, grads + (size_t)(i + 1) * BB * 2 * HW);

        float* t = RDcur; RDcur = RDnxt; RDnxt = t;
    }
}